// Round 4
// baseline (13851.376 us; speedup 1.0000x reference)
//
#include <hip/hip_runtime.h>

#define NT 256
#define NB 1024           // 1024*256 = 262144 threads = n; 4 blocks/CU (proven to launch)
#define MAXIT 100
#define RTOL_F 1e-5f
// SELL-64x1: slice = 64 rows = one wave, 1 lane per row.
// entry j of row -> sell[soff[slice] + j*64 + (row & 63)]

// ---- lightweight grid barrier (replaces cg::grid.sync) ----
// cnt/gen zeroed by hipMemsetAsync before launch. Generation-based so it is
// safely reusable; release/acquire orderings give cross-XCD visibility of all
// prior plain stores (same mechanism grid.sync uses, minus the overhead).
__device__ __forceinline__ void gbar(int* cnt, int* gen) {
    __syncthreads();
    if (threadIdx.x == 0) {
        __threadfence();
        const int g = __hip_atomic_load(gen, __ATOMIC_RELAXED, __HIP_MEMORY_SCOPE_AGENT);
        const int a = __hip_atomic_fetch_add(cnt, 1, __ATOMIC_ACQ_REL, __HIP_MEMORY_SCOPE_AGENT);
        if (a == NB - 1) {
            __hip_atomic_store(cnt, 0, __ATOMIC_RELAXED, __HIP_MEMORY_SCOPE_AGENT);
            __hip_atomic_fetch_add(gen, 1, __ATOMIC_RELEASE, __HIP_MEMORY_SCOPE_AGENT);
        } else {
            while (__hip_atomic_load(gen, __ATOMIC_ACQUIRE, __HIP_MEMORY_SCOPE_AGENT) == g)
                __builtin_amdgcn_s_sleep(2);
        }
        __threadfence();
    }
    __syncthreads();
}

// Block-wide sum, result broadcast to ALL threads (deterministic order).
__device__ __forceinline__ float block_sum_bcast(float v, float* smf) {
#pragma unroll
    for (int o = 32; o > 0; o >>= 1) v += __shfl_down(v, o);
    __syncthreads();                 // protect smf reuse across calls
    if ((threadIdx.x & 63) == 0) smf[threadIdx.x >> 6] = v;
    __syncthreads();
    return smf[0] + smf[1] + smf[2] + smf[3];
}

// Sum the NB per-block partials (identical order in every block -> identical
// result -> no cross-block divergence in loop control).
__device__ __forceinline__ float sum_parts(const float* part, float* smf) {
    const int t = threadIdx.x;
    float v = part[t] + part[t + 256] + part[t + 512] + part[t + 768];
    return block_sum_bcast(v, smf);
}

// Inclusive scan of one int per thread across the block (NT), via LDS.
__device__ __forceinline__ int block_incl_scan(int v, int* smi) {
    const int t = threadIdx.x;
    smi[t] = v;
    __syncthreads();
#pragma unroll
    for (int off = 1; off < NT; off <<= 1) {
        int add = (t >= off) ? smi[t - off] : 0;
        __syncthreads();
        v += add;
        smi[t] = v;
        __syncthreads();
    }
    return v;
}

__global__ void __launch_bounds__(NT, 4)
cg_solver_kernel(const float* __restrict__ values,
                 const float4* __restrict__ bvec,
                 const int* __restrict__ rowi,
                 const int* __restrict__ coli,
                 float4* __restrict__ x,      // = d_out
                 float4* __restrict__ r,
                 float4* __restrict__ p,
                 float4* __restrict__ q,
                 int* __restrict__ counts,    // n: row lengths
                 int* __restrict__ ridx,      // n: scatter cursors
                 int* __restrict__ jarr,      // nslice: padded slot-count per slice
                 int* __restrict__ soff,      // nslice+1: slice offsets (entries)
                 float* __restrict__ bb_part, // NB
                 float* __restrict__ pq_part, // NB
                 float* __restrict__ rr_part, // NB
                 int* __restrict__ cnt,       // barrier counter (memset 0)
                 int* __restrict__ gen,       // barrier generation (memset 0)
                 long long* __restrict__ sell,// SELL entries: low32=col, high32=val bits
                 int n, int nnz, int nslice)
{
    const int t = threadIdx.x;
    const int tid = blockIdx.x * NT + t;
    const int nth = gridDim.x * NT;          // == n
    __shared__ int smi[NT];
    __shared__ float smf[NT / 64];

    // ---- Phase A: zero counters (ws poisoned every call) ----
    for (int i = tid; i < n; i += nth) { counts[i] = 0; ridx[i] = 0; }
    gbar(cnt, gen);

    // ---- Phase B: row histogram + init r=p=b, x=0, per-block b.b partial ----
    for (int e = tid; e < nnz; e += nth) atomicAdd(&counts[rowi[e]], 1);
    float acc = 0.f;
    if (tid < n) {
        float4 bv = bvec[tid];
        r[tid] = bv;
        p[tid] = bv;
        x[tid] = make_float4(0.f, 0.f, 0.f, 0.f);
        acc = bv.x * bv.x + bv.y * bv.y + bv.z * bv.z + bv.w * bv.w;
    }
    {
        float tot = block_sum_bcast(acc, smf);
        if (t == 0) bb_part[blockIdx.x] = tot;
    }
    gbar(cnt, gen);

    // ---- Phase C: per-slice padded slot count J (multiple of 4) ----
    for (int s = tid; s < nslice; s += nth) {
        const int rb = s << 6;
        int m = 0;
#pragma unroll 4
        for (int i = 0; i < 64; ++i) m = max(m, counts[rb + i]);
        jarr[s] = (m + 3) & ~3;     // pad for unroll-4
    }
    gbar(cnt, gen);

    // ---- Phase D: block 0 scans slice sizes -> soff ----
    if (blockIdx.x == 0) {
        const int spt = (nslice + NT - 1) / NT;   // slices per thread
        const int base = t * spt;
        int local = 0;
        for (int i = 0; i < spt; ++i) {
            int s = base + i;
            if (s < nslice) local += 64 * jarr[s];
        }
        int incl = block_incl_scan(local, smi);
        int run = incl - local;
        for (int i = 0; i < spt; ++i) {
            int s = base + i;
            if (s < nslice) { soff[s] = run; run += 64 * jarr[s]; }
        }
        if (t == NT - 1) soff[nslice] = incl;     // total padded entries
    }
    gbar(cnt, gen);

    // ---- Phase E: zero-fill SELL (col=0, val=0 padding is harmless) ----
    {
        const int total = soff[nslice];
        for (int i = tid; i < total; i += nth) sell[i] = 0LL;
    }
    gbar(cnt, gen);

    // ---- Phase F: scatter COO -> SELL ----
    for (int e = tid; e < nnz; e += nth) {
        const int rr = rowi[e];
        const int i = atomicAdd(&ridx[rr], 1);
        const int pos = soff[rr >> 6] + (i << 6) + (rr & 63);
        sell[pos] = ((long long)__float_as_int(values[e]) << 32) | (unsigned int)coli[e];
    }
    gbar(cnt, gen);

    // ---- CG loop: 3 lightweight barriers / iter, no same-address atomics ----
    const int wid = tid >> 6;          // wave id == slice id
    const int lane = t & 63;
    const float bnorm2 = sum_parts(bb_part, smf);
    const float tol2 = RTOL_F * RTOL_F * bnorm2;
    float rho = bnorm2;
    int k = 0;
    while (rho > tol2 && k < MAXIT) {
        // --- phase 1: q = A p (SELL-64x1, coalesced, unroll-4) + pdot partial ---
        float4 a4 = make_float4(0.f, 0.f, 0.f, 0.f);
        {
            const long long* bp = sell + soff[wid] + lane;
            const int J = jarr[wid];
            for (int j = 0; j < J; j += 4) {
                const long long e0 = __builtin_nontemporal_load(bp + (j + 0) * 64);
                const long long e1 = __builtin_nontemporal_load(bp + (j + 1) * 64);
                const long long e2 = __builtin_nontemporal_load(bp + (j + 2) * 64);
                const long long e3 = __builtin_nontemporal_load(bp + (j + 3) * 64);
                const float4 p0 = p[(int)(e0 & 0xffffffff)];
                const float4 p1 = p[(int)(e1 & 0xffffffff)];
                const float4 p2 = p[(int)(e2 & 0xffffffff)];
                const float4 p3 = p[(int)(e3 & 0xffffffff)];
                const float v0 = __int_as_float((int)(e0 >> 32));
                const float v1 = __int_as_float((int)(e1 >> 32));
                const float v2 = __int_as_float((int)(e2 >> 32));
                const float v3 = __int_as_float((int)(e3 >> 32));
                a4.x = fmaf(v0, p0.x, a4.x); a4.y = fmaf(v0, p0.y, a4.y);
                a4.z = fmaf(v0, p0.z, a4.z); a4.w = fmaf(v0, p0.w, a4.w);
                a4.x = fmaf(v1, p1.x, a4.x); a4.y = fmaf(v1, p1.y, a4.y);
                a4.z = fmaf(v1, p1.z, a4.z); a4.w = fmaf(v1, p1.w, a4.w);
                a4.x = fmaf(v2, p2.x, a4.x); a4.y = fmaf(v2, p2.y, a4.y);
                a4.z = fmaf(v2, p2.z, a4.z); a4.w = fmaf(v2, p2.w, a4.w);
                a4.x = fmaf(v3, p3.x, a4.x); a4.y = fmaf(v3, p3.y, a4.y);
                a4.z = fmaf(v3, p3.z, a4.z); a4.w = fmaf(v3, p3.w, a4.w);
            }
        }
        {
            q[tid] = a4;
            const float4 pi = p[tid];
            float pdot = a4.x * pi.x + a4.y * pi.y + a4.z * pi.z + a4.w * pi.w;
            float tot = block_sum_bcast(pdot, smf);
            if (t == 0) pq_part[blockIdx.x] = tot;
        }
        gbar(cnt, gen);

        // --- phase 2: alpha; x += alpha p; r -= alpha q; rr partial ---
        const float alpha = rho / sum_parts(pq_part, smf);
        float rr2;
        {
            const float4 pi = p[tid];
            const float4 qi = q[tid];
            float4 ri = r[tid];
            float4 xi = x[tid];
            xi.x = fmaf(alpha, pi.x, xi.x);
            xi.y = fmaf(alpha, pi.y, xi.y);
            xi.z = fmaf(alpha, pi.z, xi.z);
            xi.w = fmaf(alpha, pi.w, xi.w);
            ri.x = fmaf(-alpha, qi.x, ri.x);
            ri.y = fmaf(-alpha, qi.y, ri.y);
            ri.z = fmaf(-alpha, qi.z, ri.z);
            ri.w = fmaf(-alpha, qi.w, ri.w);
            x[tid] = xi;
            r[tid] = ri;
            rr2 = ri.x * ri.x + ri.y * ri.y + ri.z * ri.z + ri.w * ri.w;
        }
        {
            float tot = block_sum_bcast(rr2, smf);
            if (t == 0) rr_part[blockIdx.x] = tot;
        }
        gbar(cnt, gen);

        // --- phase 3: rho_new (identical in every block); p = r + beta p ---
        const float rho_new = sum_parts(rr_part, smf);
        const float beta = rho_new / rho;
        {
            const float4 ri = r[tid];
            float4 pi = p[tid];
            pi.x = fmaf(beta, pi.x, ri.x);
            pi.y = fmaf(beta, pi.y, ri.y);
            pi.z = fmaf(beta, pi.z, ri.z);
            pi.w = fmaf(beta, pi.w, ri.w);
            p[tid] = pi;
        }
        gbar(cnt, gen);

        rho = rho_new;
        ++k;
    }
}

extern "C" void kernel_launch(void* const* d_in, const int* in_sizes, int n_in,
                              void* d_out, int out_size, void* d_ws, size_t ws_size,
                              hipStream_t stream) {
    const float* values = (const float*)d_in[0];
    const float4* bvec  = (const float4*)d_in[1];
    const int* rowi     = (const int*)d_in[2];
    const int* coli     = (const int*)d_in[3];
    const int nnz = in_sizes[0];
    const int n   = in_sizes[1] / 4;  // F = 4
    const int nslice = n / 64;        // 64 rows per wave-slice

    char* ws = (char*)d_ws;
    size_t off = 0;
    auto alloc = [&](size_t bytes) -> void* {
        off = (off + 255) & ~(size_t)255;
        void* pp = ws + off;
        off += bytes;
        return pp;
    };
    int* barr    = (int*)alloc(256);               // [0]=cnt, [1]=gen (memset 0)
    float4* r    = (float4*)alloc((size_t)n * 16);
    float4* p    = (float4*)alloc((size_t)n * 16);
    float4* q    = (float4*)alloc((size_t)n * 16);
    int* counts  = (int*)alloc((size_t)n * 4);
    int* ridx    = (int*)alloc((size_t)n * 4);
    int* jarr    = (int*)alloc((size_t)nslice * 4);
    int* soff    = (int*)alloc((size_t)(nslice + 1) * 4);
    float* bbp   = (float*)alloc((size_t)NB * 4);
    float* pqp   = (float*)alloc((size_t)NB * 4);
    float* rrp   = (float*)alloc((size_t)NB * 4);
    // SELL gets the rest of the workspace (~60 MB needed for this problem).
    off = (off + 255) & ~(size_t)255;
    long long* sell = (long long*)(ws + off);
    float4* x = (float4*)d_out;
    int* cnt = barr + 0;
    int* gen = barr + 16;   // separate cache lines

    hipMemsetAsync(barr, 0, 256, stream);   // barrier state must start at 0

    int n_ = n, nnz_ = nnz, nslice_ = nslice;
    void* args[] = {
        (void*)&values, (void*)&bvec, (void*)&rowi, (void*)&coli,
        (void*)&x, (void*)&r, (void*)&p, (void*)&q,
        (void*)&counts, (void*)&ridx, (void*)&jarr, (void*)&soff,
        (void*)&bbp, (void*)&pqp, (void*)&rrp,
        (void*)&cnt, (void*)&gen,
        (void*)&sell, (void*)&n_, (void*)&nnz_, (void*)&nslice_
    };
    hipLaunchCooperativeKernel((void*)cg_solver_kernel, dim3(NB), dim3(NT),
                               args, 0, stream);
}

// Round 5
// 2751.350 us; speedup vs baseline: 5.0344x; 5.0344x over previous
//
#include <hip/hip_runtime.h>

#define NT 1024
#define NB 256            // 256 blocks x 1024 thr = 262144 = n; 1 block/CU, co-residency trivial
#define MAXIT 100
#define RTOL_F 1e-5f
// SELL-64x1: slice = 64 rows = one wave, 1 lane per row.
// entry j of row -> sell[soff[slice] + j*64 + (row & 63)]
//
// Chronopoulos-Gear CG (2 grid barriers/iter, one fused reduction):
//   U: p=r+beta*p; s=w+beta*s; x+=alpha*p; r-=alpha*s          (registers only)
//   S: w=A*r (gather r via MALL-coherent loads); rho=r.r, mu=r.w
//   beta=rho_new/rho; alpha=rho_new/(mu - beta*rho_new/alpha_prev)
// Cross-block data in the loop: r + partials, BOTH via agent-scope relaxed
// atomics (bypass L1/L2 -> MALL is the coherence point) => loop barriers need
// NO cache fences, and the 60 MB SELL array stays L2-resident all 100 iters.

__device__ __forceinline__ unsigned long long pk2(float a, float b) {
    return ((unsigned long long)__float_as_uint(b) << 32) | (unsigned long long)__float_as_uint(a);
}

// ---- barrier core: relaxed arrival + relaxed poll (NO acquire in the spin!) ----
__device__ __forceinline__ void bar_core(int* cnt, int* gen) {
    __syncthreads();
    if (threadIdx.x == 0) {
        const int g = __hip_atomic_load(gen, __ATOMIC_RELAXED, __HIP_MEMORY_SCOPE_AGENT);
        const int a = __hip_atomic_fetch_add(cnt, 1, __ATOMIC_RELAXED, __HIP_MEMORY_SCOPE_AGENT);
        if (a == NB - 1) {
            __hip_atomic_store(cnt, 0, __ATOMIC_RELAXED, __HIP_MEMORY_SCOPE_AGENT);
            __hip_atomic_store(gen, g + 1, __ATOMIC_RELAXED, __HIP_MEMORY_SCOPE_AGENT);
        } else {
            while (__hip_atomic_load(gen, __ATOMIC_RELAXED, __HIP_MEMORY_SCOPE_AGENT) == g)
                __builtin_amdgcn_s_sleep(4);
        }
    }
    __syncthreads();
}

// heavy: full agent coherence (setup only — cached cross-block arrays)
__device__ __forceinline__ void gbar_heavy(int* cnt, int* gen) {
    __builtin_amdgcn_fence(__ATOMIC_RELEASE, "agent");   // drain + L2 writeback
    bar_core(cnt, gen);
    __builtin_amdgcn_fence(__ATOMIC_ACQUIRE, "agent");   // L1/L2 invalidate
}

// light: drain own stores (vmcnt) only; cross-block data is MALL-coherent
__device__ __forceinline__ void gbar_light(int* cnt, int* gen) {
    __builtin_amdgcn_fence(__ATOMIC_RELEASE, "workgroup"); // s_waitcnt, no cache ops
    bar_core(cnt, gen);
}

// Block-wide sum of two floats, broadcast to all threads (deterministic order).
__device__ __forceinline__ float2 block_sum2_bcast(float a, float b, float* smf) {
#pragma unroll
    for (int o = 32; o > 0; o >>= 1) { a += __shfl_down(a, o); b += __shfl_down(b, o); }
    __syncthreads();
    const int w = threadIdx.x >> 6;
    if ((threadIdx.x & 63) == 0) { smf[w] = a; smf[16 + w] = b; }
    __syncthreads();
    float ra = 0.f, rb = 0.f;
#pragma unroll
    for (int i = 0; i < 16; ++i) { ra += smf[i]; rb += smf[16 + i]; }
    return make_float2(ra, rb);
}

// Sum the NB packed (rho,mu) per-block partials — identical in every block.
__device__ __forceinline__ float2 sum_parts2(const unsigned long long* part, float* smf) {
    float a = 0.f, b = 0.f;
    if (threadIdx.x < NB) {
        unsigned long long u = __hip_atomic_load(&part[threadIdx.x], __ATOMIC_RELAXED,
                                                 __HIP_MEMORY_SCOPE_AGENT);
        a = __uint_as_float((unsigned)(u & 0xffffffffu));
        b = __uint_as_float((unsigned)(u >> 32));
    }
    return block_sum2_bcast(a, b, smf);
}

// Inclusive scan of one int per thread across the block (NT), via LDS.
__device__ __forceinline__ int block_incl_scan(int v, int* smi) {
    const int t = threadIdx.x;
    smi[t] = v;
    __syncthreads();
    for (int off = 1; off < NT; off <<= 1) {
        int add = (t >= off) ? smi[t - off] : 0;
        __syncthreads();
        v += add;
        smi[t] = v;
        __syncthreads();
    }
    return v;
}

// MALL-coherent gather of one r row (float4 as 2x8B relaxed agent loads).
__device__ __forceinline__ float4 gather_r(const unsigned long long* rq, int c) {
    unsigned long long lo = __hip_atomic_load(&rq[2 * c + 0], __ATOMIC_RELAXED, __HIP_MEMORY_SCOPE_AGENT);
    unsigned long long hi = __hip_atomic_load(&rq[2 * c + 1], __ATOMIC_RELAXED, __HIP_MEMORY_SCOPE_AGENT);
    return make_float4(__uint_as_float((unsigned)(lo & 0xffffffffu)),
                       __uint_as_float((unsigned)(lo >> 32)),
                       __uint_as_float((unsigned)(hi & 0xffffffffu)),
                       __uint_as_float((unsigned)(hi >> 32)));
}

__global__ void __launch_bounds__(NT, 4)
cg_solver_kernel(const float* __restrict__ values,
                 const float4* __restrict__ bvec,
                 const int* __restrict__ rowi,
                 const int* __restrict__ coli,
                 float4* __restrict__ x,           // = d_out
                 unsigned long long* __restrict__ rst, // r as 2x8B per row (MALL-coherent)
                 int* __restrict__ counts,
                 int* __restrict__ ridx,
                 int* __restrict__ jarr,
                 int* __restrict__ soff,
                 unsigned long long* __restrict__ part, // NB packed (rho,mu) partials
                 int* __restrict__ cnt, int* __restrict__ gen,
                 long long* __restrict__ sell,
                 int n, int nnz, int nslice)
{
    const int t = threadIdx.x;
    const int tid = blockIdx.x * NT + t;
    const int nth = gridDim.x * NT;          // == n
    __shared__ int smi[NT];
    __shared__ float smf[32];

    // ---- Phase A: zero counters ----
    for (int i = tid; i < n; i += nth) { counts[i] = 0; ridx[i] = 0; }
    gbar_heavy(cnt, gen);

    // ---- Phase B: histogram + keep b in registers; x=0; publish r=b to MALL ----
    for (int e = tid; e < nnz; e += nth) atomicAdd(&counts[rowi[e]], 1);
    float4 rv = bvec[tid];                   // r_0 = b (register-resident)
    x[tid] = make_float4(0.f, 0.f, 0.f, 0.f);
    __hip_atomic_store(&rst[2 * tid + 0], pk2(rv.x, rv.y), __ATOMIC_RELAXED, __HIP_MEMORY_SCOPE_AGENT);
    __hip_atomic_store(&rst[2 * tid + 1], pk2(rv.z, rv.w), __ATOMIC_RELAXED, __HIP_MEMORY_SCOPE_AGENT);
    gbar_heavy(cnt, gen);

    // ---- Phase C: per-slice padded slot count (multiple of 4) ----
    for (int s = tid; s < nslice; s += nth) {
        const int rb = s << 6;
        int m = 0;
#pragma unroll 4
        for (int i = 0; i < 64; ++i) m = max(m, counts[rb + i]);
        jarr[s] = (m + 3) & ~3;
    }
    gbar_heavy(cnt, gen);

    // ---- Phase D: block 0 scans slice sizes -> soff ----
    if (blockIdx.x == 0) {
        const int spt = (nslice + NT - 1) / NT;
        const int base = t * spt;
        int local = 0;
        for (int i = 0; i < spt; ++i) {
            int s = base + i;
            if (s < nslice) local += 64 * jarr[s];
        }
        int incl = block_incl_scan(local, smi);
        int run = incl - local;
        for (int i = 0; i < spt; ++i) {
            int s = base + i;
            if (s < nslice) { soff[s] = run; run += 64 * jarr[s]; }
        }
        if (t == NT - 1) soff[nslice] = incl;
    }
    gbar_heavy(cnt, gen);

    // ---- Phase E: zero-fill SELL ----
    {
        const int total = soff[nslice];
        for (int i = tid; i < total; i += nth) sell[i] = 0LL;
    }
    gbar_heavy(cnt, gen);

    // ---- Phase F: scatter COO -> SELL ----
    for (int e = tid; e < nnz; e += nth) {
        const int rr = rowi[e];
        const int i = atomicAdd(&ridx[rr], 1);
        const int pos = soff[rr >> 6] + (i << 6) + (rr & 63);
        sell[pos] = ((long long)__float_as_int(values[e]) << 32) | (unsigned int)coli[e];
    }
    gbar_heavy(cnt, gen);

    // ---- CG-CG iteration state (all owner-local state in registers) ----
    const int wid = tid >> 6;
    const int lane = t & 63;
    const long long* __restrict__ bp0 = sell + soff[wid] + lane;
    const int J = jarr[wid];
    const unsigned long long* __restrict__ rq = rst;

    float4 pv = make_float4(0.f, 0.f, 0.f, 0.f);
    float4 sv = make_float4(0.f, 0.f, 0.f, 0.f);
    float4 xv = make_float4(0.f, 0.f, 0.f, 0.f);
    float4 wv;

    // ---- init-S: w0 = A r0; rho0 = r.r, mu0 = r.w ----
    {
        float4 a4 = make_float4(0.f, 0.f, 0.f, 0.f);
        for (int j = 0; j < J; j += 4) {
            const long long e0 = bp0[(j + 0) * 64];
            const long long e1 = bp0[(j + 1) * 64];
            const long long e2 = bp0[(j + 2) * 64];
            const long long e3 = bp0[(j + 3) * 64];
            const float4 g0 = gather_r(rq, (int)(e0 & 0xffffffff));
            const float4 g1 = gather_r(rq, (int)(e1 & 0xffffffff));
            const float4 g2 = gather_r(rq, (int)(e2 & 0xffffffff));
            const float4 g3 = gather_r(rq, (int)(e3 & 0xffffffff));
            const float v0 = __int_as_float((int)(e0 >> 32));
            const float v1 = __int_as_float((int)(e1 >> 32));
            const float v2 = __int_as_float((int)(e2 >> 32));
            const float v3 = __int_as_float((int)(e3 >> 32));
            a4.x = fmaf(v0, g0.x, a4.x); a4.y = fmaf(v0, g0.y, a4.y);
            a4.z = fmaf(v0, g0.z, a4.z); a4.w = fmaf(v0, g0.w, a4.w);
            a4.x = fmaf(v1, g1.x, a4.x); a4.y = fmaf(v1, g1.y, a4.y);
            a4.z = fmaf(v1, g1.z, a4.z); a4.w = fmaf(v1, g1.w, a4.w);
            a4.x = fmaf(v2, g2.x, a4.x); a4.y = fmaf(v2, g2.y, a4.y);
            a4.z = fmaf(v2, g2.z, a4.z); a4.w = fmaf(v2, g2.w, a4.w);
            a4.x = fmaf(v3, g3.x, a4.x); a4.y = fmaf(v3, g3.y, a4.y);
            a4.z = fmaf(v3, g3.z, a4.z); a4.w = fmaf(v3, g3.w, a4.w);
        }
        wv = a4;
        float rho_p = rv.x * rv.x + rv.y * rv.y + rv.z * rv.z + rv.w * rv.w;
        float mu_p  = rv.x * wv.x + rv.y * wv.y + rv.z * wv.z + rv.w * wv.w;
        float2 tot = block_sum2_bcast(rho_p, mu_p, smf);
        if (t == 0)
            __hip_atomic_store(&part[blockIdx.x], pk2(tot.x, tot.y), __ATOMIC_RELAXED, __HIP_MEMORY_SCOPE_AGENT);
    }
    gbar_light(cnt, gen);

    float2 rm = sum_parts2(part, smf);       // (rho0, mu0) — identical in all blocks
    float rho = rm.x;
    const float tol2 = RTOL_F * RTOL_F * rho;
    float alpha = rho / rm.y;
    float beta = 0.f;

    int k = 0;
    while (rho > tol2 && k < MAXIT) {
        // --- U: pure register updates; publish new r to MALL ---
        pv.x = fmaf(beta, pv.x, rv.x); pv.y = fmaf(beta, pv.y, rv.y);
        pv.z = fmaf(beta, pv.z, rv.z); pv.w = fmaf(beta, pv.w, rv.w);
        sv.x = fmaf(beta, sv.x, wv.x); sv.y = fmaf(beta, sv.y, wv.y);
        sv.z = fmaf(beta, sv.z, wv.z); sv.w = fmaf(beta, sv.w, wv.w);
        xv.x = fmaf(alpha, pv.x, xv.x); xv.y = fmaf(alpha, pv.y, xv.y);
        xv.z = fmaf(alpha, pv.z, xv.z); xv.w = fmaf(alpha, pv.w, xv.w);
        rv.x = fmaf(-alpha, sv.x, rv.x); rv.y = fmaf(-alpha, sv.y, rv.y);
        rv.z = fmaf(-alpha, sv.z, rv.z); rv.w = fmaf(-alpha, sv.w, rv.w);
        x[tid] = xv;
        __hip_atomic_store(&rst[2 * tid + 0], pk2(rv.x, rv.y), __ATOMIC_RELAXED, __HIP_MEMORY_SCOPE_AGENT);
        __hip_atomic_store(&rst[2 * tid + 1], pk2(rv.z, rv.w), __ATOMIC_RELAXED, __HIP_MEMORY_SCOPE_AGENT);
        gbar_light(cnt, gen);

        // --- S: w = A r + fused (r.r, r.w) partials ---
        float4 a4 = make_float4(0.f, 0.f, 0.f, 0.f);
        for (int j = 0; j < J; j += 4) {
            const long long e0 = bp0[(j + 0) * 64];
            const long long e1 = bp0[(j + 1) * 64];
            const long long e2 = bp0[(j + 2) * 64];
            const long long e3 = bp0[(j + 3) * 64];
            const float4 g0 = gather_r(rq, (int)(e0 & 0xffffffff));
            const float4 g1 = gather_r(rq, (int)(e1 & 0xffffffff));
            const float4 g2 = gather_r(rq, (int)(e2 & 0xffffffff));
            const float4 g3 = gather_r(rq, (int)(e3 & 0xffffffff));
            const float v0 = __int_as_float((int)(e0 >> 32));
            const float v1 = __int_as_float((int)(e1 >> 32));
            const float v2 = __int_as_float((int)(e2 >> 32));
            const float v3 = __int_as_float((int)(e3 >> 32));
            a4.x = fmaf(v0, g0.x, a4.x); a4.y = fmaf(v0, g0.y, a4.y);
            a4.z = fmaf(v0, g0.z, a4.z); a4.w = fmaf(v0, g0.w, a4.w);
            a4.x = fmaf(v1, g1.x, a4.x); a4.y = fmaf(v1, g1.y, a4.y);
            a4.z = fmaf(v1, g1.z, a4.z); a4.w = fmaf(v1, g1.w, a4.w);
            a4.x = fmaf(v2, g2.x, a4.x); a4.y = fmaf(v2, g2.y, a4.y);
            a4.z = fmaf(v2, g2.z, a4.z); a4.w = fmaf(v2, g2.w, a4.w);
            a4.x = fmaf(v3, g3.x, a4.x); a4.y = fmaf(v3, g3.y, a4.y);
            a4.z = fmaf(v3, g3.z, a4.z); a4.w = fmaf(v3, g3.w, a4.w);
        }
        wv = a4;
        {
            float rho_p = rv.x * rv.x + rv.y * rv.y + rv.z * rv.z + rv.w * rv.w;
            float mu_p  = rv.x * wv.x + rv.y * wv.y + rv.z * wv.z + rv.w * wv.w;
            float2 tot = block_sum2_bcast(rho_p, mu_p, smf);
            if (t == 0)
                __hip_atomic_store(&part[blockIdx.x], pk2(tot.x, tot.y), __ATOMIC_RELAXED, __HIP_MEMORY_SCOPE_AGENT);
        }
        gbar_light(cnt, gen);

        // --- scalars: identical in every block (same partials, same order) ---
        rm = sum_parts2(part, smf);          // (rho_{k+1}, mu_{k+1})
        beta = rm.x / rho;
        alpha = rm.x / (rm.y - beta * rm.x / alpha);
        rho = rm.x;
        ++k;
    }
}

extern "C" void kernel_launch(void* const* d_in, const int* in_sizes, int n_in,
                              void* d_out, int out_size, void* d_ws, size_t ws_size,
                              hipStream_t stream) {
    const float* values = (const float*)d_in[0];
    const float4* bvec  = (const float4*)d_in[1];
    const int* rowi     = (const int*)d_in[2];
    const int* coli     = (const int*)d_in[3];
    const int nnz = in_sizes[0];
    const int n   = in_sizes[1] / 4;  // F = 4
    const int nslice = n / 64;

    char* ws = (char*)d_ws;
    size_t off = 0;
    auto alloc = [&](size_t bytes) -> void* {
        off = (off + 255) & ~(size_t)255;
        void* pp = ws + off;
        off += bytes;
        return pp;
    };
    int* barr    = (int*)alloc(256);                  // [0]=cnt, [16]=gen
    unsigned long long* rst = (unsigned long long*)alloc((size_t)n * 16);
    unsigned long long* part = (unsigned long long*)alloc((size_t)NB * 8);
    int* counts  = (int*)alloc((size_t)n * 4);
    int* ridx    = (int*)alloc((size_t)n * 4);
    int* jarr    = (int*)alloc((size_t)nslice * 4);
    int* soff    = (int*)alloc((size_t)(nslice + 1) * 4);
    off = (off + 255) & ~(size_t)255;
    long long* sell = (long long*)(ws + off);         // rest of ws (~60 MB)
    float4* x = (float4*)d_out;
    int* cnt = barr + 0;
    int* gen = barr + 16;

    hipMemsetAsync(barr, 0, 256, stream);

    int n_ = n, nnz_ = nnz, nslice_ = nslice;
    void* args[] = {
        (void*)&values, (void*)&bvec, (void*)&rowi, (void*)&coli,
        (void*)&x, (void*)&rst,
        (void*)&counts, (void*)&ridx, (void*)&jarr, (void*)&soff,
        (void*)&part, (void*)&cnt, (void*)&gen,
        (void*)&sell, (void*)&n_, (void*)&nnz_, (void*)&nslice_
    };
    hipLaunchCooperativeKernel((void*)cg_solver_kernel, dim3(NB), dim3(NT),
                               args, 0, stream);
}

// Round 6
// 2517.378 us; speedup vs baseline: 5.5023x; 1.0929x over previous
//
#include <hip/hip_runtime.h>

#define NT 1024
#define NB 256            // 256 blocks x 1024 thr = 262144 = n; 1 block/CU
#define MAXIT 100
#define RTOL_F 1e-5f
// SELL-64x1: slice = 64 rows = one wave, 1 lane per row.
// entry j of row -> sell[soff[slice] + j*64 + (row & 63)]
//
// Chronopoulos-Gear CG, 2 distributed-flag barriers/iter. All cross-block loop
// data (r, partials, flags) moves via agent-scope relaxed atomics -> MALL is
// the coherence point, loop barriers need NO cache maintenance, and the ~60 MB
// SELL array stays L2-resident across all iterations.

__device__ __forceinline__ unsigned long long pk2(float a, float b) {
    return ((unsigned long long)__float_as_uint(b) << 32) | (unsigned long long)__float_as_uint(a);
}

// ---- distributed flag barrier ----
// Each block publishes flags[b]=seq (own slot, no contention); wave 0 polls all
// NB flags (4 per lane). __syncthreads() drains each wave's vmcnt first, so all
// prior global stores are at the coherence point before the flag goes up.
__device__ __forceinline__ void fbar(int* flags, int seq) {
    __syncthreads();
    if (threadIdx.x == 0)
        __hip_atomic_store(&flags[blockIdx.x], seq, __ATOMIC_RELAXED, __HIP_MEMORY_SCOPE_AGENT);
    if (threadIdx.x < 64) {
        const int b4 = threadIdx.x << 2;
        for (;;) {
            const int f0 = __hip_atomic_load(&flags[b4 + 0], __ATOMIC_RELAXED, __HIP_MEMORY_SCOPE_AGENT);
            const int f1 = __hip_atomic_load(&flags[b4 + 1], __ATOMIC_RELAXED, __HIP_MEMORY_SCOPE_AGENT);
            const int f2 = __hip_atomic_load(&flags[b4 + 2], __ATOMIC_RELAXED, __HIP_MEMORY_SCOPE_AGENT);
            const int f3 = __hip_atomic_load(&flags[b4 + 3], __ATOMIC_RELAXED, __HIP_MEMORY_SCOPE_AGENT);
            const bool ok = (f0 >= seq) && (f1 >= seq) && (f2 >= seq) && (f3 >= seq);
            if (__all(ok)) break;
            __builtin_amdgcn_s_sleep(1);
        }
    }
    __syncthreads();
}

// heavy variant for setup phases: full agent cache maintenance around arrival
__device__ __forceinline__ void fbar_heavy(int* flags, int seq) {
    __builtin_amdgcn_fence(__ATOMIC_RELEASE, "agent");
    fbar(flags, seq);
    __builtin_amdgcn_fence(__ATOMIC_ACQUIRE, "agent");
}

// Block-wide sum of two floats, broadcast to all threads (deterministic order).
__device__ __forceinline__ float2 block_sum2_bcast(float a, float b, float* smf) {
#pragma unroll
    for (int o = 32; o > 0; o >>= 1) { a += __shfl_down(a, o); b += __shfl_down(b, o); }
    __syncthreads();
    const int w = threadIdx.x >> 6;
    if ((threadIdx.x & 63) == 0) { smf[w] = a; smf[16 + w] = b; }
    __syncthreads();
    float ra = 0.f, rb = 0.f;
#pragma unroll
    for (int i = 0; i < 16; ++i) { ra += smf[i]; rb += smf[16 + i]; }
    return make_float2(ra, rb);
}

// Sum the NB packed (rho,mu) per-block partials — identical in every block.
__device__ __forceinline__ float2 sum_parts2(const unsigned long long* part, float* smf) {
    float a = 0.f, b = 0.f;
    if (threadIdx.x < NB) {
        unsigned long long u = __hip_atomic_load(&part[threadIdx.x], __ATOMIC_RELAXED,
                                                 __HIP_MEMORY_SCOPE_AGENT);
        a = __uint_as_float((unsigned)(u & 0xffffffffu));
        b = __uint_as_float((unsigned)(u >> 32));
    }
    return block_sum2_bcast(a, b, smf);
}

// Inclusive scan of one int per thread across the block (NT), via LDS.
__device__ __forceinline__ int block_incl_scan(int v, int* smi) {
    const int t = threadIdx.x;
    smi[t] = v;
    __syncthreads();
    for (int off = 1; off < NT; off <<= 1) {
        int add = (t >= off) ? smi[t - off] : 0;
        __syncthreads();
        v += add;
        smi[t] = v;
        __syncthreads();
    }
    return v;
}

// MALL-coherent gather of one r row (float4 as 2x8B relaxed agent loads).
__device__ __forceinline__ float4 gather_r(const unsigned long long* rq, int c) {
    unsigned long long lo = __hip_atomic_load(&rq[2 * c + 0], __ATOMIC_RELAXED, __HIP_MEMORY_SCOPE_AGENT);
    unsigned long long hi = __hip_atomic_load(&rq[2 * c + 1], __ATOMIC_RELAXED, __HIP_MEMORY_SCOPE_AGENT);
    return make_float4(__uint_as_float((unsigned)(lo & 0xffffffffu)),
                       __uint_as_float((unsigned)(lo >> 32)),
                       __uint_as_float((unsigned)(hi & 0xffffffffu)),
                       __uint_as_float((unsigned)(hi >> 32)));
}

// One SELL row SpMV, unroll-8 (J is a multiple of 8): 8 sell loads + 8 gathers
// in flight per step for MLP.
__device__ __forceinline__ float4 spmv_row(const long long* __restrict__ bp0, int J,
                                           const unsigned long long* __restrict__ rq) {
    float4 a4 = make_float4(0.f, 0.f, 0.f, 0.f);
    for (int j = 0; j < J; j += 8) {
        long long e[8];
#pragma unroll
        for (int u = 0; u < 8; ++u) e[u] = bp0[(j + u) * 64];
        float4 g[8];
#pragma unroll
        for (int u = 0; u < 8; ++u) g[u] = gather_r(rq, (int)(e[u] & 0xffffffffLL));
#pragma unroll
        for (int u = 0; u < 8; ++u) {
            const float v = __int_as_float((int)(e[u] >> 32));
            a4.x = fmaf(v, g[u].x, a4.x);
            a4.y = fmaf(v, g[u].y, a4.y);
            a4.z = fmaf(v, g[u].z, a4.z);
            a4.w = fmaf(v, g[u].w, a4.w);
        }
    }
    return a4;
}

__global__ void __launch_bounds__(NT, 4)
cg_solver_kernel(const float* __restrict__ values,
                 const float4* __restrict__ bvec,
                 const int* __restrict__ rowi,
                 const int* __restrict__ coli,
                 float4* __restrict__ x,               // = d_out
                 unsigned long long* __restrict__ rst, // r as 2x8B per row (MALL-coherent)
                 int* __restrict__ counts,
                 int* __restrict__ ridx,
                 int* __restrict__ jarr,
                 int* __restrict__ soff,
                 unsigned long long* __restrict__ part, // NB packed (rho,mu) partials
                 int* __restrict__ flags,               // NB barrier flags (memset 0)
                 long long* __restrict__ sell,
                 int n, int nnz, int nslice)
{
    const int t = threadIdx.x;
    const int tid = blockIdx.x * NT + t;
    const int nth = gridDim.x * NT;          // == n
    __shared__ int smi[NT];
    __shared__ float smf[32];
    int seq = 0;

    // ---- Phase A: zero counters ----
    for (int i = tid; i < n; i += nth) { counts[i] = 0; ridx[i] = 0; }
    fbar_heavy(flags, ++seq);

    // ---- Phase B: histogram + keep b in registers; publish r=b to MALL ----
    for (int e = tid; e < nnz; e += nth) atomicAdd(&counts[rowi[e]], 1);
    float4 rv = bvec[tid];                   // r_0 = b (register-resident)
    __hip_atomic_store(&rst[2 * tid + 0], pk2(rv.x, rv.y), __ATOMIC_RELAXED, __HIP_MEMORY_SCOPE_AGENT);
    __hip_atomic_store(&rst[2 * tid + 1], pk2(rv.z, rv.w), __ATOMIC_RELAXED, __HIP_MEMORY_SCOPE_AGENT);
    fbar_heavy(flags, ++seq);

    // ---- Phase C: per-slice padded slot count (multiple of 8 for unroll-8) ----
    for (int s = tid; s < nslice; s += nth) {
        const int rb = s << 6;
        int m = 0;
#pragma unroll 4
        for (int i = 0; i < 64; ++i) m = max(m, counts[rb + i]);
        jarr[s] = (m + 7) & ~7;
    }
    fbar_heavy(flags, ++seq);

    // ---- Phase D: block 0 scans slice sizes -> soff ----
    if (blockIdx.x == 0) {
        const int spt = (nslice + NT - 1) / NT;
        const int base = t * spt;
        int local = 0;
        for (int i = 0; i < spt; ++i) {
            int s = base + i;
            if (s < nslice) local += 64 * jarr[s];
        }
        int incl = block_incl_scan(local, smi);
        int run = incl - local;
        for (int i = 0; i < spt; ++i) {
            int s = base + i;
            if (s < nslice) { soff[s] = run; run += 64 * jarr[s]; }
        }
        if (t == NT - 1) soff[nslice] = incl;
    }
    fbar_heavy(flags, ++seq);

    // ---- Phase E: zero-fill SELL ----
    {
        const int total = soff[nslice];
        for (int i = tid; i < total; i += nth) sell[i] = 0LL;
    }
    fbar_heavy(flags, ++seq);

    // ---- Phase F: scatter COO -> SELL ----
    for (int e = tid; e < nnz; e += nth) {
        const int rr = rowi[e];
        const int i = atomicAdd(&ridx[rr], 1);
        const int pos = soff[rr >> 6] + (i << 6) + (rr & 63);
        sell[pos] = ((long long)__float_as_int(values[e]) << 32) | (unsigned int)coli[e];
    }
    fbar_heavy(flags, ++seq);

    // ---- CG-CG state (owner-local state in registers; x written once at end) ----
    const int wid = tid >> 6;
    const int lane = t & 63;
    const long long* __restrict__ bp0 = sell + soff[wid] + lane;
    const int J = jarr[wid];
    const unsigned long long* __restrict__ rq = rst;

    float4 pv = make_float4(0.f, 0.f, 0.f, 0.f);
    float4 sv = make_float4(0.f, 0.f, 0.f, 0.f);
    float4 xv = make_float4(0.f, 0.f, 0.f, 0.f);
    float4 wv;

    // ---- init-S: w0 = A r0; rho0 = r.r, mu0 = r.w ----
    {
        wv = spmv_row(bp0, J, rq);
        float rho_p = rv.x * rv.x + rv.y * rv.y + rv.z * rv.z + rv.w * rv.w;
        float mu_p  = rv.x * wv.x + rv.y * wv.y + rv.z * wv.z + rv.w * wv.w;
        float2 tot = block_sum2_bcast(rho_p, mu_p, smf);
        if (t == 0)
            __hip_atomic_store(&part[blockIdx.x], pk2(tot.x, tot.y), __ATOMIC_RELAXED, __HIP_MEMORY_SCOPE_AGENT);
    }
    fbar(flags, ++seq);

    float2 rm = sum_parts2(part, smf);       // (rho0, mu0) — identical in all blocks
    float rho = rm.x;
    const float tol2 = RTOL_F * RTOL_F * rho;
    float alpha = rho / rm.y;
    float beta = 0.f;

    int k = 0;
    while (rho > tol2 && k < MAXIT) {
        // --- U: register updates; publish new r to MALL ---
        pv.x = fmaf(beta, pv.x, rv.x); pv.y = fmaf(beta, pv.y, rv.y);
        pv.z = fmaf(beta, pv.z, rv.z); pv.w = fmaf(beta, pv.w, rv.w);
        sv.x = fmaf(beta, sv.x, wv.x); sv.y = fmaf(beta, sv.y, wv.y);
        sv.z = fmaf(beta, sv.z, wv.z); sv.w = fmaf(beta, sv.w, wv.w);
        xv.x = fmaf(alpha, pv.x, xv.x); xv.y = fmaf(alpha, pv.y, xv.y);
        xv.z = fmaf(alpha, pv.z, xv.z); xv.w = fmaf(alpha, pv.w, xv.w);
        rv.x = fmaf(-alpha, sv.x, rv.x); rv.y = fmaf(-alpha, sv.y, rv.y);
        rv.z = fmaf(-alpha, sv.z, rv.z); rv.w = fmaf(-alpha, sv.w, rv.w);
        __hip_atomic_store(&rst[2 * tid + 0], pk2(rv.x, rv.y), __ATOMIC_RELAXED, __HIP_MEMORY_SCOPE_AGENT);
        __hip_atomic_store(&rst[2 * tid + 1], pk2(rv.z, rv.w), __ATOMIC_RELAXED, __HIP_MEMORY_SCOPE_AGENT);
        fbar(flags, ++seq);   // all r published before any gather

        // --- S: w = A r + fused (r.r, r.w) partials ---
        wv = spmv_row(bp0, J, rq);
        {
            float rho_p = rv.x * rv.x + rv.y * rv.y + rv.z * rv.z + rv.w * rv.w;
            float mu_p  = rv.x * wv.x + rv.y * wv.y + rv.z * wv.z + rv.w * wv.w;
            float2 tot = block_sum2_bcast(rho_p, mu_p, smf);
            if (t == 0)
                __hip_atomic_store(&part[blockIdx.x], pk2(tot.x, tot.y), __ATOMIC_RELAXED, __HIP_MEMORY_SCOPE_AGENT);
        }
        fbar(flags, ++seq);   // partials published => all gathers of r_k done

        // --- scalars: identical in every block ---
        rm = sum_parts2(part, smf);          // (rho_{k+1}, mu_{k+1})
        beta = rm.x / rho;
        alpha = rm.x / (rm.y - beta * rm.x / alpha);
        rho = rm.x;
        ++k;
    }

    x[tid] = xv;   // single write of the solution
}

extern "C" void kernel_launch(void* const* d_in, const int* in_sizes, int n_in,
                              void* d_out, int out_size, void* d_ws, size_t ws_size,
                              hipStream_t stream) {
    const float* values = (const float*)d_in[0];
    const float4* bvec  = (const float4*)d_in[1];
    const int* rowi     = (const int*)d_in[2];
    const int* coli     = (const int*)d_in[3];
    const int nnz = in_sizes[0];
    const int n   = in_sizes[1] / 4;  // F = 4
    const int nslice = n / 64;

    char* ws = (char*)d_ws;
    size_t off = 0;
    auto alloc = [&](size_t bytes) -> void* {
        off = (off + 255) & ~(size_t)255;
        void* pp = ws + off;
        off += bytes;
        return pp;
    };
    int* flags   = (int*)alloc((size_t)NB * 4);       // barrier flags (memset 0)
    unsigned long long* rst = (unsigned long long*)alloc((size_t)n * 16);
    unsigned long long* part = (unsigned long long*)alloc((size_t)NB * 8);
    int* counts  = (int*)alloc((size_t)n * 4);
    int* ridx    = (int*)alloc((size_t)n * 4);
    int* jarr    = (int*)alloc((size_t)nslice * 4);
    int* soff    = (int*)alloc((size_t)(nslice + 1) * 4);
    off = (off + 255) & ~(size_t)255;
    long long* sell = (long long*)(ws + off);         // rest of ws (~65 MB)
    float4* x = (float4*)d_out;

    hipMemsetAsync(flags, 0, (size_t)NB * 4, stream);

    int n_ = n, nnz_ = nnz, nslice_ = nslice;
    void* args[] = {
        (void*)&values, (void*)&bvec, (void*)&rowi, (void*)&coli,
        (void*)&x, (void*)&rst,
        (void*)&counts, (void*)&ridx, (void*)&jarr, (void*)&soff,
        (void*)&part, (void*)&flags,
        (void*)&sell, (void*)&n_, (void*)&nnz_, (void*)&nslice_
    };
    hipLaunchCooperativeKernel((void*)cg_solver_kernel, dim3(NB), dim3(NT),
                               args, 0, stream);
}

// Round 7
// 2040.461 us; speedup vs baseline: 6.7884x; 1.2337x over previous
//
#include <hip/hip_runtime.h>

#define NT 1024
#define NB 256            // 256 blocks x 1024 thr = 262144 = n; 1 block/CU
#define MAXIT 100
#define RTOL_F 1e-5f
// SELL-64x1: slice = 64 rows = one wave, 1 lane per row.
// entry j of row -> sell[soff[slice] + j*64 + (row & 63)]
//
// Chronopoulos-Gear CG, 2 distributed-flag barriers/iter. Cross-block loop data
// (r, partials, flags) moves through the MALL coherence point: r via 16B
// uncached (sc0 sc1) loads/stores, partials/flags via agent-scope atomics.
// Loop barriers therefore need NO cache maintenance and the ~65 MB SELL array
// stays L2/L3-resident across all iterations.

typedef float f4 __attribute__((ext_vector_type(4)));

__device__ __forceinline__ unsigned long long pk2(float a, float b) {
    return ((unsigned long long)__float_as_uint(b) << 32) | (unsigned long long)__float_as_uint(a);
}

// 16B uncached (coherence-point) load: ISSUE ONLY — result invalid until wait16.
__device__ __forceinline__ void ld16_cc(const f4* a, f4& d) {
    asm volatile("global_load_dwordx4 %0, %1, off sc0 sc1" : "=v"(d) : "v"(a));
}
// Wait for all VMEM; ties the 8 gather results so uses can't be hoisted above.
__device__ __forceinline__ void wait16x8(f4& a, f4& b, f4& c, f4& d,
                                         f4& e, f4& f, f4& g, f4& h) {
    asm volatile("s_waitcnt vmcnt(0)"
                 : "+v"(a), "+v"(b), "+v"(c), "+v"(d),
                   "+v"(e), "+v"(f), "+v"(g), "+v"(h));
}
// 16B uncached (coherence-point) store.
__device__ __forceinline__ void st16_cc(f4* a, f4 v) {
    asm volatile("global_store_dwordx4 %0, %1, off sc0 sc1" :: "v"(a), "v"(v) : "memory");
}

// ---- distributed flag barrier ----
// Each block publishes flags[b]=seq (own slot); wave 0 polls all NB flags.
// __syncthreads() drains vmcnt first, so all prior stores (incl. asm sc0sc1
// stores — hardware vmcnt covers them) are at the coherence point.
__device__ __forceinline__ void fbar(int* flags, int seq) {
    __syncthreads();
    if (threadIdx.x == 0)
        __hip_atomic_store(&flags[blockIdx.x], seq, __ATOMIC_RELAXED, __HIP_MEMORY_SCOPE_AGENT);
    if (threadIdx.x < 64) {
        const int b4 = threadIdx.x << 2;
        for (;;) {
            const int f0 = __hip_atomic_load(&flags[b4 + 0], __ATOMIC_RELAXED, __HIP_MEMORY_SCOPE_AGENT);
            const int f1 = __hip_atomic_load(&flags[b4 + 1], __ATOMIC_RELAXED, __HIP_MEMORY_SCOPE_AGENT);
            const int f2 = __hip_atomic_load(&flags[b4 + 2], __ATOMIC_RELAXED, __HIP_MEMORY_SCOPE_AGENT);
            const int f3 = __hip_atomic_load(&flags[b4 + 3], __ATOMIC_RELAXED, __HIP_MEMORY_SCOPE_AGENT);
            const bool ok = (f0 >= seq) && (f1 >= seq) && (f2 >= seq) && (f3 >= seq);
            if (__all(ok)) break;
            __builtin_amdgcn_s_sleep(1);
        }
    }
    __syncthreads();
}

// heavy variant for setup phases: full agent cache maintenance around arrival
__device__ __forceinline__ void fbar_heavy(int* flags, int seq) {
    __builtin_amdgcn_fence(__ATOMIC_RELEASE, "agent");
    fbar(flags, seq);
    __builtin_amdgcn_fence(__ATOMIC_ACQUIRE, "agent");
}

// Block-wide sum of two floats, broadcast to all threads (deterministic order).
__device__ __forceinline__ float2 block_sum2_bcast(float a, float b, float* smf) {
#pragma unroll
    for (int o = 32; o > 0; o >>= 1) { a += __shfl_down(a, o); b += __shfl_down(b, o); }
    __syncthreads();
    const int w = threadIdx.x >> 6;
    if ((threadIdx.x & 63) == 0) { smf[w] = a; smf[16 + w] = b; }
    __syncthreads();
    float ra = 0.f, rb = 0.f;
#pragma unroll
    for (int i = 0; i < 16; ++i) { ra += smf[i]; rb += smf[16 + i]; }
    return make_float2(ra, rb);
}

// Sum the NB packed (rho,mu) per-block partials — identical in every block.
__device__ __forceinline__ float2 sum_parts2(const unsigned long long* part, float* smf) {
    float a = 0.f, b = 0.f;
    if (threadIdx.x < NB) {
        unsigned long long u = __hip_atomic_load(&part[threadIdx.x], __ATOMIC_RELAXED,
                                                 __HIP_MEMORY_SCOPE_AGENT);
        a = __uint_as_float((unsigned)(u & 0xffffffffu));
        b = __uint_as_float((unsigned)(u >> 32));
    }
    return block_sum2_bcast(a, b, smf);
}

// Inclusive scan of one int per thread across the block (NT), via LDS.
__device__ __forceinline__ int block_incl_scan(int v, int* smi) {
    const int t = threadIdx.x;
    smi[t] = v;
    __syncthreads();
    for (int off = 1; off < NT; off <<= 1) {
        int add = (t >= off) ? smi[t - off] : 0;
        __syncthreads();
        v += add;
        smi[t] = v;
        __syncthreads();
    }
    return v;
}

// One SELL row SpMV, unroll-8 (J multiple of 8): 8 sell loads + 8x16B uncached
// gathers in flight per step.
__device__ __forceinline__ f4 spmv_row(const long long* __restrict__ bp0, int J,
                                       const f4* __restrict__ rq) {
    f4 a4 = {0.f, 0.f, 0.f, 0.f};
    for (int j = 0; j < J; j += 8) {
        long long e[8];
#pragma unroll
        for (int u = 0; u < 8; ++u) e[u] = bp0[(j + u) * 64];
        f4 g0, g1, g2, g3, g4, g5, g6, g7;
        ld16_cc(rq + (int)(e[0] & 0xffffffffLL), g0);
        ld16_cc(rq + (int)(e[1] & 0xffffffffLL), g1);
        ld16_cc(rq + (int)(e[2] & 0xffffffffLL), g2);
        ld16_cc(rq + (int)(e[3] & 0xffffffffLL), g3);
        ld16_cc(rq + (int)(e[4] & 0xffffffffLL), g4);
        ld16_cc(rq + (int)(e[5] & 0xffffffffLL), g5);
        ld16_cc(rq + (int)(e[6] & 0xffffffffLL), g6);
        ld16_cc(rq + (int)(e[7] & 0xffffffffLL), g7);
        wait16x8(g0, g1, g2, g3, g4, g5, g6, g7);
        const float v0 = __int_as_float((int)(e[0] >> 32));
        const float v1 = __int_as_float((int)(e[1] >> 32));
        const float v2 = __int_as_float((int)(e[2] >> 32));
        const float v3 = __int_as_float((int)(e[3] >> 32));
        const float v4 = __int_as_float((int)(e[4] >> 32));
        const float v5 = __int_as_float((int)(e[5] >> 32));
        const float v6 = __int_as_float((int)(e[6] >> 32));
        const float v7 = __int_as_float((int)(e[7] >> 32));
        a4 += v0 * g0; a4 += v1 * g1; a4 += v2 * g2; a4 += v3 * g3;
        a4 += v4 * g4; a4 += v5 * g5; a4 += v6 * g6; a4 += v7 * g7;
    }
    return a4;
}

__global__ void __launch_bounds__(NT, 4)
cg_solver_kernel(const float* __restrict__ values,
                 const f4* __restrict__ bvec,
                 const int* __restrict__ rowi,
                 const int* __restrict__ coli,
                 f4* __restrict__ x,                   // = d_out
                 f4* __restrict__ rst,                 // r rows (MALL-coherent)
                 int* __restrict__ counts,
                 int* __restrict__ ridx,
                 int* __restrict__ jarr,
                 int* __restrict__ soff,
                 unsigned long long* __restrict__ part, // NB packed (rho,mu) partials
                 int* __restrict__ flags,               // NB barrier flags (memset 0)
                 long long* __restrict__ sell,
                 int n, int nnz, int nslice)
{
    const int t = threadIdx.x;
    const int tid = blockIdx.x * NT + t;
    const int nth = gridDim.x * NT;          // == n
    __shared__ int smi[NT];
    __shared__ float smf[32];
    int seq = 0;

    // ---- Phase A: zero counters ----
    for (int i = tid; i < n; i += nth) { counts[i] = 0; ridx[i] = 0; }
    fbar_heavy(flags, ++seq);

    // ---- Phase B: histogram + keep b in registers; publish r=b to MALL ----
    for (int e = tid; e < nnz; e += nth) atomicAdd(&counts[rowi[e]], 1);
    f4 rv = bvec[tid];                       // r_0 = b (register-resident)
    st16_cc(&rst[tid], rv);
    fbar_heavy(flags, ++seq);

    // ---- Phase C: per-slice padded slot count (multiple of 8 for unroll-8) ----
    for (int s = tid; s < nslice; s += nth) {
        const int rb = s << 6;
        int m = 0;
#pragma unroll 4
        for (int i = 0; i < 64; ++i) m = max(m, counts[rb + i]);
        jarr[s] = (m + 7) & ~7;
    }
    fbar_heavy(flags, ++seq);

    // ---- Phase D: block 0 scans slice sizes -> soff ----
    if (blockIdx.x == 0) {
        const int spt = (nslice + NT - 1) / NT;
        const int base = t * spt;
        int local = 0;
        for (int i = 0; i < spt; ++i) {
            int s = base + i;
            if (s < nslice) local += 64 * jarr[s];
        }
        int incl = block_incl_scan(local, smi);
        int run = incl - local;
        for (int i = 0; i < spt; ++i) {
            int s = base + i;
            if (s < nslice) { soff[s] = run; run += 64 * jarr[s]; }
        }
        if (t == NT - 1) soff[nslice] = incl;
    }
    fbar_heavy(flags, ++seq);

    // ---- Phase E: zero-fill SELL ----
    {
        const int total = soff[nslice];
        for (int i = tid; i < total; i += nth) sell[i] = 0LL;
    }
    fbar_heavy(flags, ++seq);

    // ---- Phase F: scatter COO -> SELL ----
    for (int e = tid; e < nnz; e += nth) {
        const int rr = rowi[e];
        const int i = atomicAdd(&ridx[rr], 1);
        const int pos = soff[rr >> 6] + (i << 6) + (rr & 63);
        sell[pos] = ((long long)__float_as_int(values[e]) << 32) | (unsigned int)coli[e];
    }
    fbar_heavy(flags, ++seq);

    // ---- CG-CG state (owner-local state in registers; x written once at end) ----
    const int wid = tid >> 6;
    const int lane = t & 63;
    const long long* __restrict__ bp0 = sell + soff[wid] + lane;
    const int J = jarr[wid];
    const f4* __restrict__ rq = rst;

    f4 pv = {0.f, 0.f, 0.f, 0.f};
    f4 sv = {0.f, 0.f, 0.f, 0.f};
    f4 xv = {0.f, 0.f, 0.f, 0.f};
    f4 wv;

    // ---- init-S: w0 = A r0; rho0 = r.r, mu0 = r.w ----
    {
        wv = spmv_row(bp0, J, rq);
        float rho_p = rv.x * rv.x + rv.y * rv.y + rv.z * rv.z + rv.w * rv.w;
        float mu_p  = rv.x * wv.x + rv.y * wv.y + rv.z * wv.z + rv.w * wv.w;
        float2 tot = block_sum2_bcast(rho_p, mu_p, smf);
        if (t == 0)
            __hip_atomic_store(&part[blockIdx.x], pk2(tot.x, tot.y), __ATOMIC_RELAXED, __HIP_MEMORY_SCOPE_AGENT);
    }
    fbar(flags, ++seq);

    float2 rm = sum_parts2(part, smf);       // (rho0, mu0) — identical in all blocks
    float rho = rm.x;
    const float tol2 = RTOL_F * RTOL_F * rho;
    float alpha = rho / rm.y;
    float beta = 0.f;

    int k = 0;
    while (rho > tol2 && k < MAXIT) {
        // --- U: register recurrences; publish new r to MALL ---
        pv = rv + beta * pv;
        sv = wv + beta * sv;
        xv = xv + alpha * pv;
        rv = rv - alpha * sv;
        st16_cc(&rst[tid], rv);
        fbar(flags, ++seq);   // all r published before any gather

        // --- S: w = A r + fused (r.r, r.w) partials ---
        wv = spmv_row(bp0, J, rq);
        {
            float rho_p = rv.x * rv.x + rv.y * rv.y + rv.z * rv.z + rv.w * rv.w;
            float mu_p  = rv.x * wv.x + rv.y * wv.y + rv.z * wv.z + rv.w * wv.w;
            float2 tot = block_sum2_bcast(rho_p, mu_p, smf);
            if (t == 0)
                __hip_atomic_store(&part[blockIdx.x], pk2(tot.x, tot.y), __ATOMIC_RELAXED, __HIP_MEMORY_SCOPE_AGENT);
        }
        fbar(flags, ++seq);   // partials published => all gathers of r_k done

        // --- scalars: identical in every block ---
        rm = sum_parts2(part, smf);          // (rho_{k+1}, mu_{k+1})
        beta = rm.x / rho;
        alpha = rm.x / (rm.y - beta * rm.x / alpha);
        rho = rm.x;
        ++k;
    }

    x[tid] = xv;   // single write of the solution
}

extern "C" void kernel_launch(void* const* d_in, const int* in_sizes, int n_in,
                              void* d_out, int out_size, void* d_ws, size_t ws_size,
                              hipStream_t stream) {
    const float* values = (const float*)d_in[0];
    const f4* bvec      = (const f4*)d_in[1];
    const int* rowi     = (const int*)d_in[2];
    const int* coli     = (const int*)d_in[3];
    const int nnz = in_sizes[0];
    const int n   = in_sizes[1] / 4;  // F = 4
    const int nslice = n / 64;

    char* ws = (char*)d_ws;
    size_t off = 0;
    auto alloc = [&](size_t bytes) -> void* {
        off = (off + 255) & ~(size_t)255;
        void* pp = ws + off;
        off += bytes;
        return pp;
    };
    int* flags   = (int*)alloc((size_t)NB * 4);       // barrier flags (memset 0)
    f4* rst      = (f4*)alloc((size_t)n * 16);
    unsigned long long* part = (unsigned long long*)alloc((size_t)NB * 8);
    int* counts  = (int*)alloc((size_t)n * 4);
    int* ridx    = (int*)alloc((size_t)n * 4);
    int* jarr    = (int*)alloc((size_t)nslice * 4);
    int* soff    = (int*)alloc((size_t)(nslice + 1) * 4);
    off = (off + 255) & ~(size_t)255;
    long long* sell = (long long*)(ws + off);         // rest of ws (~65 MB)
    f4* x = (f4*)d_out;

    hipMemsetAsync(flags, 0, (size_t)NB * 4, stream);

    int n_ = n, nnz_ = nnz, nslice_ = nslice;
    void* args[] = {
        (void*)&values, (void*)&bvec, (void*)&rowi, (void*)&coli,
        (void*)&x, (void*)&rst,
        (void*)&counts, (void*)&ridx, (void*)&jarr, (void*)&soff,
        (void*)&part, (void*)&flags,
        (void*)&sell, (void*)&n_, (void*)&nnz_, (void*)&nslice_
    };
    hipLaunchCooperativeKernel((void*)cg_solver_kernel, dim3(NB), dim3(NT),
                               args, 0, stream);
}